// Round 14
// baseline (173.426 us; speedup 1.0000x reference)
//
#include <hip/hip_runtime.h>

// Problem constants: B=8, N_IN=256, N=8192, D=64, K=512
#define NIN    256
#define NCOL   8192
#define DDIM   64
#define KCODES 512
#define NCTOT  65536                         // total columns = B*N
#define ZQ_ELEMS (8ull * 64ull * 8192ull)    // zq floats; hist follows

typedef float f32x2 __attribute__((ext_vector_type(2)));

// ---------------------------------------------------------------------------
// K1 prep (round-11 verified): Wt[i][d] = W[d][i]; embT[d][k] = emb[k][d];
// emb_sq[k] = ||emb[k]||^2 (ascending-d, bit-exact); hist_out = ind_hist;
// cand[] = ~0 (u64 argmin accumulators, re-init every call).
// ---------------------------------------------------------------------------
__global__ __launch_bounds__(256) void vq_prep(const float* __restrict__ W,
                                               const float* __restrict__ emb,
                                               const float* __restrict__ ind_hist,
                                               float* __restrict__ Wt,
                                               float* __restrict__ embT,
                                               float* __restrict__ emb_sq,
                                               unsigned long long* __restrict__ cand,
                                               float* __restrict__ hist_out)
{
    const int t = blockIdx.x * 256 + threadIdx.x;   // t < 32768
    cand[t]         = ~0ull;
    cand[t + 32768] = ~0ull;
    if (t < NIN * DDIM) {
        int i = t >> 6;
        int d = t & 63;
        Wt[t] = W[d * NIN + i];
    }
    {
        int d = t >> 9;          // 0..63
        int k = t & 511;         // 0..511
        embT[t] = emb[k * DDIM + d];
    }
    if (t < KCODES) {
        const float* __restrict__ ek = emb + t * DDIM;
        float s = 0.f;
        #pragma unroll
        for (int d = 0; d < DDIM; ++d) s = fmaf(ek[d], ek[d], s);
        emb_sq[t] = s;
        hist_out[t] = ind_hist[t];
    }
}

// ---------------------------------------------------------------------------
// K2 conv (round-13 verified): 1024 blocks x 512 thr / 8 waves, cap 64.
// Wave w -> d-slice [8w,8w+8) for 64 cols (lane=col, Wt s_load, ascending-i
// fmaf — bit-identical ze). Writes ze to OUTPUT buffer (b,d,n), coalesced.
// ---------------------------------------------------------------------------
__global__ __launch_bounds__(512, 8) void vq_conv(const float* __restrict__ z,
                                                  const float* __restrict__ Wt,
                                                  float* __restrict__ out)
{
    const int tid = threadIdx.x;
    const int cl  = tid & 63;
    const int w   = __builtin_amdgcn_readfirstlane(tid >> 6);   // 0..7
    const int C   = blockIdx.x * 64 + cl;
    const int b   = C >> 13;
    const int n   = C & (NCOL - 1);

    const float* __restrict__ zp = z + (size_t)b * NIN * NCOL + n;
    const float* __restrict__ wp = Wt + w * 8;

    float acc[8];
    #pragma unroll
    for (int j = 0; j < 8; ++j) acc[j] = 0.f;

    for (int i = 0; i < NIN; i += 4) {
        float z0 = zp[(size_t)(i + 0) * NCOL];
        float z1 = zp[(size_t)(i + 1) * NCOL];
        float z2 = zp[(size_t)(i + 2) * NCOL];
        float z3 = zp[(size_t)(i + 3) * NCOL];
        const float* __restrict__ w0 = wp + (size_t)(i + 0) * DDIM;  // s_load
        const float* __restrict__ w1 = wp + (size_t)(i + 1) * DDIM;
        const float* __restrict__ w2 = wp + (size_t)(i + 2) * DDIM;
        const float* __restrict__ w3 = wp + (size_t)(i + 3) * DDIM;
        #pragma unroll
        for (int j = 0; j < 8; ++j) {
            float a = acc[j];
            a = fmaf(w0[j], z0, a);   // ascending i: bit-exact
            a = fmaf(w1[j], z1, a);
            a = fmaf(w2[j], z2, a);
            a = fmaf(w3[j], z3, a);
            acc[j] = a;
        }
    }

    float* __restrict__ op = out + ((size_t)b * DDIM + w * 8) * NCOL + n;
    #pragma unroll
    for (int j = 0; j < 8; ++j) op[(size_t)j * NCOL] = acc[j];
}

// ---------------------------------------------------------------------------
// K3 search: exact round-11 structure (verified, best measured: 78.5us/75%)
// with ONE change: the 16-scalar-FMA inner block is replaced by 8 packed
// v_pk_fma_f32 (dual fp32 FMA — the spec 157.3 TF fp32 rate is the packed
// rate; scalar v_fma runs at half). Each half computes fmaf(ep[k], zj, acc)
// with the identical ascending-d chain -> bit-exact vs all passing rounds.
// emb operand stays a wave-uniform SGPR pair (s_load); zj duplicated into
// a VGPR pair (1 mov per 8 pk-FMAs). 2048 blocks x 256, cap 128.
// ---------------------------------------------------------------------------
__global__ __launch_bounds__(256, 4) void vq_search(const float* __restrict__ zeb,
                                                    const float* __restrict__ embT,
                                                    const float* __restrict__ emb_sq,
                                                    unsigned long long* __restrict__ cand)
{
    __shared__ float ze_lds[64][DDIM + 1];   // stride 65: b32 conflict-free

    const int tid = threadIdx.x;
    const int C0  = (blockIdx.x >> 1) * 64;
    const int h   = blockIdx.x & 1;
    const int b   = C0 >> 13;                // 64-col tile never crosses b
    const int n0  = C0 & (NCOL - 1);

    // coop load ze tile from conv output (round-11 verified pattern)
    {
        const int r  = tid >> 2;
        const int cc = (tid & 3) * 16;
        const float4* __restrict__ src = reinterpret_cast<const float4*>(
            zeb + ((size_t)b * DDIM + r) * NCOL + n0 + cc);
        #pragma unroll
        for (int v = 0; v < 4; ++v) {
            float4 x = src[v];
            ze_lds[cc + 4 * v + 0][r] = x.x;
            ze_lds[cc + 4 * v + 1][r] = x.y;
            ze_lds[cc + 4 * v + 2][r] = x.z;
            ze_lds[cc + 4 * v + 3][r] = x.w;
        }
    }
    __syncthreads();

    const int cl = tid & 63;
    const int w  = __builtin_amdgcn_readfirstlane(tid >> 6);

    // zesq: ascending-d chain (bit-exact)
    float zesq = 0.f;
    #pragma unroll
    for (int d = 0; d < DDIM; ++d) {
        float zd = ze_lds[cl][d];
        zesq = fmaf(zd, zd, zesq);
    }

    // wave w owns k in [256h + 64w, +64)
    const int k0 = h * (KCODES / 2) + w * 64;
    float best  = 3.4e38f;
    int   bestk = k0;

    for (int t4 = 0; t4 < 4; ++t4) {                  // 4 k-tiles of 16
        const int kt = k0 + t4 * 16;

        f32x2 acc2[8];
        #pragma unroll
        for (int p = 0; p < 8; ++p) { acc2[p].x = 0.f; acc2[p].y = 0.f; }

        #pragma unroll
        for (int dc = 0; dc < 8; ++dc) {              // 8 static d-chunks of 8
            float zd[8];
            #pragma unroll
            for (int j = 0; j < 8; ++j)
                zd[j] = ze_lds[cl][dc * 8 + j];       // static idx: VGPR

            #pragma unroll
            for (int j = 0; j < 8; ++j) {
                const f32x2* __restrict__ ep2 = reinterpret_cast<const f32x2*>(
                    embT + (size_t)(dc * 8 + j) * KCODES + kt);  // uniform
                f32x2 zjp;                            // (zj, zj) VGPR pair
                zjp.x = zd[j];
                zjp.y = zd[j];
                #pragma unroll
                for (int p = 0; p < 8; ++p) {
                    f32x2 e2 = ep2[p];                // SGPR pair (s_load)
                    asm("v_pk_fma_f32 %0, %1, %2, %0"
                        : "+v"(acc2[p])
                        : "s"(e2), "v"(zjp));         // 2x IEEE fp32 FMA
                }
            }
        }

        #pragma unroll
        for (int p = 0; p < 8; ++p) {                 // ascending k: first-min
            const int k = kt + 2 * p;
            float d0 = (zesq + emb_sq[k])     - 2.0f * acc2[p].x;  // ref order
            if (d0 < best) { best = d0; bestk = k; }
            float d1 = (zesq + emb_sq[k + 1]) - 2.0f * acc2[p].y;
            if (d1 < best) { best = d1; bestk = k + 1; }
        }
    }

    unsigned u   = __float_as_uint(best);
    unsigned enc = u ^ ((unsigned)((int)u >> 31) | 0x80000000u);  // order-map
    unsigned long long pk =
        ((unsigned long long)enc << 32) | (unsigned)bestk;
    atomicMin(&cand[C0 + cl], pk);
}

// ---------------------------------------------------------------------------
// K4 final (new, no LDS restage): 1024 blocks x 256. Thread = (column C,
// d-quarter dq): reads winner k, gathers emb[fk] row (float4, L1/L2-hot),
// streams ze from the conv output (coalesced: lane = n) and writes zq in
// place. zq = ze + (e - ze) — same expression as all passing rounds.
// 1 hist atomic per column (dq==0).
// ---------------------------------------------------------------------------
__global__ __launch_bounds__(256, 4) void vq_final2(const float* __restrict__ emb,
                                                    const unsigned long long* __restrict__ cand,
                                                    float* __restrict__ out,
                                                    float* __restrict__ hist)
{
    const int tid = threadIdx.x;
    const int cl  = tid & 63;                 // column within tile
    const int dq  = tid >> 6;                 // d-quarter 0..3
    const int C   = blockIdx.x * 64 + cl;
    const int b   = C >> 13;
    const int n   = C & (NCOL - 1);

    const int fk = (int)(unsigned)cand[C];
    if (dq == 0) atomicAdd(hist + fk, 1.0f);

    const float4* __restrict__ eb =
        reinterpret_cast<const float4*>(emb + (size_t)fk * DDIM) + dq * 4;
    float* __restrict__ op = out + ((size_t)b * DDIM + dq * 16) * NCOL + n;
    #pragma unroll
    for (int v = 0; v < 4; ++v) {
        float4 e = eb[v];                     // per-lane gather, L1/L2-hot
        float z0 = op[(size_t)(4 * v + 0) * NCOL];   // coalesced ze read
        float z1 = op[(size_t)(4 * v + 1) * NCOL];
        float z2 = op[(size_t)(4 * v + 2) * NCOL];
        float z3 = op[(size_t)(4 * v + 3) * NCOL];
        op[(size_t)(4 * v + 0) * NCOL] = z0 + (e.x - z0);
        op[(size_t)(4 * v + 1) * NCOL] = z1 + (e.y - z1);
        op[(size_t)(4 * v + 2) * NCOL] = z2 + (e.z - z2);
        op[(size_t)(4 * v + 3) * NCOL] = z3 + (e.w - z3);
    }
}

// ---------------------------------------------------------------------------
extern "C" void kernel_launch(void* const* d_in, const int* in_sizes, int n_in,
                              void* d_out, int out_size, void* d_ws, size_t ws_size,
                              hipStream_t stream)
{
    const float* z        = (const float*)d_in[0];  // (8, 256, 8192)
    const float* W        = (const float*)d_in[1];  // (64, 256)
    const float* emb      = (const float*)d_in[2];  // (512, 64)
    const float* ind_hist = (const float*)d_in[3];  // (512,)

    float* out  = (float*)d_out;                    // zq then hist
    float* hist = out + ZQ_ELEMS;

    unsigned long long* cand = (unsigned long long*)d_ws;          // 512 KB
    float* Wt     = (float*)((char*)d_ws + NCTOT * 8);             // 64 KB
    float* embT   = Wt + NIN * DDIM;                               // 128 KB
    float* emb_sq = embT + DDIM * KCODES;                          // 2 KB

    hipLaunchKernelGGL(vq_prep, dim3(128), dim3(256), 0, stream,
                       W, emb, ind_hist, Wt, embT, emb_sq, cand, hist);

    // conv: 64 cols/block, 8 waves -> 32 waves/CU (HBM-latency phase)
    hipLaunchKernelGGL(vq_conv, dim3(1024), dim3(512), 0, stream,
                       z, Wt, out);

    // search: 64-col tile x k-half -> 2048 blocks (round-11 verified shape)
    hipLaunchKernelGGL(vq_search, dim3(2048), dim3(256), 0, stream,
                       out, embT, emb_sq, cand);

    // final: in-place zq + hist, no LDS restage
    hipLaunchKernelGGL(vq_final2, dim3(1024), dim3(256), 0, stream,
                       emb, cand, out, hist);
}